// Round 5
// baseline (705.439 us; speedup 1.0000x reference)
//
#include <hip/hip_runtime.h>
#include <hip/hip_bf16.h>

#define N_NODES 100000
#define N_EDGES 1200000
#define DCH 64

#define SCAN_BLOCK 1024
#define NB_SCAN ((N_NODES + SCAN_BLOCK - 1) / SCAN_BLOCK)   // 98 blocks

// Edge-chunk config shared by hist / bcount / semisort.
#define HB 96
#define CHUNK ((N_EDGES + HB - 1) / HB)        // 12500 edges per chunk-block
#define HALF_BINS 50000
#define HALF_WORDS 12500

// Bucketing: 256 nodes per bucket.
#define BNODES 256
#define KBUK ((N_NODES + BNODES - 1) / BNODES)   // 391

// Workspace layout (bytes), max extent ~20.8 MB (26.4 MB known-safe):
//   deg_out  : int N           [0,        400000)
//   deg_in   : int N           [400000,   800000)
//   row_ptr  : int N+1         [800000,  1200004)
//   bpart    : int HB*KBUK     [1200008, 1350152)
//   blockoff : int HB*KBUK     [1350152, 1500296)
//   bsums    : int 256         [1600008, 1601032)
//   flag     : int 1           [1601032, 1601036)
//   esort    : u32 E           [1601040, 6401040)
//   hs       : bf16 N*64       [6401040, 19201040)
//   part     : hist partials, overlays esort+hs (dead after reduce)
#define OFF_DEGOUT   0
#define OFF_DEGIN    400000
#define OFF_ROWPTR   800000
#define OFF_BPART    1200008
#define OFF_BLOCKOFF 1350152
#define OFF_BSUMS    1600008
#define OFF_FLAG     1601032
#define OFF_ESORT    1601040
#define OFF_HS       6401040
#define OFF_PART     1601040   // overlays esort+hs; consumed before they're written

__device__ __forceinline__ float load_f(const void* p, int i, int f32) {
    if (f32) return ((const float*)p)[i];
    return __bfloat162float(((const __hip_bfloat16*)p)[i]);
}

// Runtime dtype sniff (resolved fp32 on this harness; kept for safety).
__global__ void detect_kernel(const void* __restrict__ x, int* __restrict__ flag) {
    __shared__ int cnt[256];
    int tid = threadIdx.x;
    const unsigned short* u = (const unsigned short*)x;
    int c = 0;
    for (int i = tid * 16; i < tid * 16 + 16; ++i) {
        unsigned short v = u[2 * i];
        int e = (v >> 7) & 0xFF;
        if (e >= 141) c++;
    }
    cnt[tid] = c;
    __syncthreads();
    for (int s = 128; s > 0; s >>= 1) {
        if (tid < s) cnt[tid] += cnt[tid + s];
        __syncthreads();
    }
    if (tid == 0) *flag = (cnt[0] > 256) ? 1 : 0;
}

// Per-block LDS byte-counter degree histogram (no fabric atomics).
__global__ __launch_bounds__(1024)
void hist_kernel(const int* __restrict__ src,
                 const int* __restrict__ dst,
                 unsigned int* __restrict__ part) {
    __shared__ unsigned int h[HALF_WORDS];   // 50 KB
    int tid = threadIdx.x;
    int b = blockIdx.x, half = blockIdx.y, which = blockIdx.z;
    const int* idx = which ? dst : src;
    for (int w = tid; w < HALF_WORDS; w += 1024) h[w] = 0;
    __syncthreads();
    int lo = half * HALF_BINS, hi = lo + HALF_BINS;
    int e0 = b * CHUNK;
    int e1 = e0 + CHUNK; if (e1 > N_EDGES) e1 = N_EDGES;
    for (int e = e0 + tid; e < e1; e += 1024) {
        int n = idx[e];
        if (n >= lo && n < hi) {
            int r = n - lo;
            atomicAdd(&h[r >> 2], 1u << ((r & 3) * 8));
        }
    }
    __syncthreads();
    unsigned int* slice = part + (size_t)(((which * HB + b) * 2 + half)) * HALF_WORDS;
    for (int w = tid; w < HALF_WORDS; w += 1024) slice[w] = h[w];
}

// Sum packed-byte partials -> deg arrays (byte lanes can't carry: max deg ~40).
__global__ void reduce_deg_kernel(const unsigned int* __restrict__ part,
                                  int* __restrict__ deg_out,
                                  int* __restrict__ deg_in) {
    int g = blockIdx.x * 256 + threadIdx.x;
    if (g >= 2 * HALF_WORDS) return;
    int half = (g >= HALF_WORDS) ? 1 : 0;
    int w = g - half * HALF_WORDS;
#pragma unroll 2
    for (int which = 0; which < 2; ++which) {
        unsigned int acc = 0;
        for (int b = 0; b < HB; ++b)
            acc += part[(size_t)(((which * HB + b) * 2 + half)) * HALF_WORDS + w];
        int* deg = which ? deg_in : deg_out;
        int node = g * 4;
#pragma unroll
        for (int j = 0; j < 4; ++j)
            deg[node + j] = (int)((acc >> (j * 8)) & 0xFF);
    }
}

// hs[i][c] = bf16( (x[i]@W)[c] * rsqrt(max(deg_out[i],1)) )
__global__ void gemm_scale_kernel(const void* __restrict__ x,
                                  const void* __restrict__ W,
                                  const int* __restrict__ deg_out,
                                  const int* __restrict__ flag,
                                  __hip_bfloat16* __restrict__ hs) {
    int f32 = *flag;
    int lane = threadIdx.x & 63;
    int wave = (blockIdx.x * blockDim.x + threadIdx.x) >> 6;
    int nwaves = (gridDim.x * blockDim.x) >> 6;

    float wcol[DCH];
#pragma unroll
    for (int k = 0; k < DCH; ++k)
        wcol[k] = load_f(W, k * DCH + lane, f32);

    for (int node = wave; node < N_NODES; node += nwaves) {
        float xv = load_f(x, node * DCH + lane, f32);
        float sum = 0.0f;
#pragma unroll
        for (int k = 0; k < DCH; ++k) {
            float xk = __int_as_float(__builtin_amdgcn_readlane(__float_as_int(xv), k));
            sum = fmaf(xk, wcol[k], sum);
        }
        float nrm = rsqrtf(fmaxf((float)deg_out[node], 1.0f));
        hs[node * DCH + lane] = __float2bfloat16(sum * nrm);
    }
}

// Exclusive scan of deg_in -> row_ptr (bucket bases come from row_ptr[k*256]).
__global__ void scanA_kernel(const int* __restrict__ deg_in,
                             int* __restrict__ row_ptr,
                             int* __restrict__ bsums) {
    __shared__ int s[256];
    int t = threadIdx.x;
    int base = blockIdx.x * SCAN_BLOCK + t * 4;
    int v0 = (base + 0 < N_NODES) ? deg_in[base + 0] : 0;
    int v1 = (base + 1 < N_NODES) ? deg_in[base + 1] : 0;
    int v2 = (base + 2 < N_NODES) ? deg_in[base + 2] : 0;
    int v3 = (base + 3 < N_NODES) ? deg_in[base + 3] : 0;
    int tsum = v0 + v1 + v2 + v3;
    s[t] = tsum;
    __syncthreads();
    for (int off = 1; off < 256; off <<= 1) {
        int add = (t >= off) ? s[t - off] : 0;
        __syncthreads();
        s[t] += add;
        __syncthreads();
    }
    int excl = s[t] - tsum;
    if (t == 255) bsums[blockIdx.x] = s[t];
    int p = excl;
    if (base + 0 < N_NODES) row_ptr[base + 0] = p; p += v0;
    if (base + 1 < N_NODES) row_ptr[base + 1] = p; p += v1;
    if (base + 2 < N_NODES) row_ptr[base + 2] = p; p += v2;
    if (base + 3 < N_NODES) row_ptr[base + 3] = p;
}

__global__ void scanB_kernel(int* __restrict__ bsums) {
    __shared__ int s[256];
    int t = threadIdx.x;
    int v = (t < NB_SCAN) ? bsums[t] : 0;
    s[t] = v;
    __syncthreads();
    for (int off = 1; off < 256; off <<= 1) {
        int add = (t >= off) ? s[t - off] : 0;
        __syncthreads();
        s[t] += add;
        __syncthreads();
    }
    if (t < NB_SCAN) bsums[t] = s[t] - v;
}

__global__ void scanC_kernel(int* __restrict__ row_ptr,
                             const int* __restrict__ bsums) {
    int off = bsums[blockIdx.x];
    int base = blockIdx.x * SCAN_BLOCK + threadIdx.x * 4;
#pragma unroll
    for (int j = 0; j < 4; ++j) {
        int idx = base + j;
        if (idx < N_NODES) row_ptr[idx] += off;
    }
    if (blockIdx.x == 0 && threadIdx.x == 0) row_ptr[N_NODES] = N_EDGES;
}

// B1: per-chunk bucket counts (LDS, no fabric atomics).
__global__ __launch_bounds__(1024)
void bcount_kernel(const int* __restrict__ dst, int* __restrict__ bpart) {
    __shared__ int cnt[KBUK];
    int tid = threadIdx.x, blk = blockIdx.x;
    for (int i = tid; i < KBUK; i += 1024) cnt[i] = 0;
    __syncthreads();
    int e0 = blk * CHUNK;
    int e1 = e0 + CHUNK; if (e1 > N_EDGES) e1 = N_EDGES;
    for (int e = e0 + tid; e < e1; e += 1024)
        atomicAdd(&cnt[dst[e] >> 8], 1);
    __syncthreads();
    for (int i = tid; i < KBUK; i += 1024) bpart[blk * KBUK + i] = cnt[i];
}

// B2: per-(chunk,bucket) write offsets. Bucket base = row_ptr[k*256];
// prefix over chunk blocks. Parallel over k, serial (96) over chunks.
__global__ void boffset_kernel(const int* __restrict__ bpart,
                               const int* __restrict__ row_ptr,
                               int* __restrict__ blockoff) {
    int k = blockIdx.x * 256 + threadIdx.x;
    if (k >= KBUK) return;
    int off = row_ptr[k * BNODES];
    for (int b = 0; b < HB; ++b) {
        blockoff[b * KBUK + k] = off;
        off += bpart[b * KBUK + k];
    }
}

// B3: semi-sort edges into bucket order with LDS cursors (no fabric atomics).
// Packed u32: bits 0..16 = src, bits 24..31 = dst & 255.
__global__ __launch_bounds__(1024)
void semisort_kernel(const int* __restrict__ src,
                     const int* __restrict__ dst,
                     const int* __restrict__ blockoff,
                     unsigned int* __restrict__ esort) {
    __shared__ int cur[KBUK];
    int tid = threadIdx.x, blk = blockIdx.x;
    for (int i = tid; i < KBUK; i += 1024) cur[i] = blockoff[blk * KBUK + i];
    __syncthreads();
    int e0 = blk * CHUNK;
    int e1 = e0 + CHUNK; if (e1 > N_EDGES) e1 = N_EDGES;
    for (int e = e0 + tid; e < e1; e += 1024) {
        int d = dst[e];
        int pos = atomicAdd(&cur[d >> 8], 1);
        esort[pos] = (unsigned int)src[e] | ((unsigned int)(d & 255) << 24);
    }
}

// G: one block per 256-node bucket; LDS fp32 tile accumulation via ds_add_f32;
// fused norm+bias+relu epilogue. No accumulator chain -> deep load pipelining.
__global__ __launch_bounds__(1024)
void bucket_gather_kernel(const __hip_bfloat16* __restrict__ hs,
                          const int* __restrict__ row_ptr,
                          const unsigned int* __restrict__ esort,
                          const int* __restrict__ deg_in,
                          const void* __restrict__ b,
                          const int* __restrict__ flag,
                          void* __restrict__ out) {
    __shared__ float tile[BNODES * DCH];   // 64 KB
    int k = blockIdx.x;
    int tid = threadIdx.x;
    int lane = tid & 63, wv = tid >> 6;
    for (int i = tid; i < BNODES * DCH; i += 1024) tile[i] = 0.0f;
    __syncthreads();

    int nlo = k * BNODES;
    int nhi = nlo + BNODES; if (nhi > N_NODES) nhi = N_NODES;
    int beg = row_ptr[nlo];
    int end = row_ptr[nhi];
    const unsigned short* hsu = (const unsigned short*)hs;

    int nb = (end - beg + 63) >> 6;
    for (int ib = wv; ib < nb; ib += 16) {
        int e0 = beg + (ib << 6);
        int nj = end - e0; if (nj > 64) nj = 64;
        int v = (lane < nj) ? (int)esort[e0 + lane] : 0;
        int j = 0;
        for (; j + 4 <= nj; j += 4) {
            int v0 = __shfl(v, j), v1 = __shfl(v, j + 1);
            int v2 = __shfl(v, j + 2), v3 = __shfl(v, j + 3);
            unsigned short r0 = hsu[(v0 & 0xFFFFFF) * DCH + lane];
            unsigned short r1 = hsu[(v1 & 0xFFFFFF) * DCH + lane];
            unsigned short r2 = hsu[(v2 & 0xFFFFFF) * DCH + lane];
            unsigned short r3 = hsu[(v3 & 0xFFFFFF) * DCH + lane];
            float f0 = __uint_as_float((unsigned int)r0 << 16);
            float f1 = __uint_as_float((unsigned int)r1 << 16);
            float f2 = __uint_as_float((unsigned int)r2 << 16);
            float f3 = __uint_as_float((unsigned int)r3 << 16);
            __hip_atomic_fetch_add(&tile[((unsigned)v0 >> 24) * DCH + lane], f0,
                                   __ATOMIC_RELAXED, __HIP_MEMORY_SCOPE_WORKGROUP);
            __hip_atomic_fetch_add(&tile[((unsigned)v1 >> 24) * DCH + lane], f1,
                                   __ATOMIC_RELAXED, __HIP_MEMORY_SCOPE_WORKGROUP);
            __hip_atomic_fetch_add(&tile[((unsigned)v2 >> 24) * DCH + lane], f2,
                                   __ATOMIC_RELAXED, __HIP_MEMORY_SCOPE_WORKGROUP);
            __hip_atomic_fetch_add(&tile[((unsigned)v3 >> 24) * DCH + lane], f3,
                                   __ATOMIC_RELAXED, __HIP_MEMORY_SCOPE_WORKGROUP);
        }
        for (; j < nj; ++j) {
            int vj = __shfl(v, j);
            unsigned short r = hsu[(vj & 0xFFFFFF) * DCH + lane];
            float f = __uint_as_float((unsigned int)r << 16);
            __hip_atomic_fetch_add(&tile[((unsigned)vj >> 24) * DCH + lane], f,
                                   __ATOMIC_RELAXED, __HIP_MEMORY_SCOPE_WORKGROUP);
        }
    }
    __syncthreads();

    int f32 = *flag;
    for (int i = tid; i < BNODES * DCH; i += 1024) {
        int n = nlo + (i >> 6);
        if (n < N_NODES) {
            int c = i & 63;
            float nrm = rsqrtf(fmaxf((float)deg_in[n], 1.0f));
            float o = fmaxf(tile[i] * nrm + load_f(b, c, f32), 0.0f);
            if (f32) ((float*)out)[n * DCH + c] = o;
            else     ((__hip_bfloat16*)out)[n * DCH + c] = __float2bfloat16(o);
        }
    }
}

extern "C" void kernel_launch(void* const* d_in, const int* in_sizes, int n_in,
                              void* d_out, int out_size, void* d_ws, size_t ws_size,
                              hipStream_t stream) {
    const void* x   = d_in[0];
    const void* W   = d_in[1];
    const void* b   = d_in[2];
    const int*  src = (const int*)d_in[3];
    const int*  dst = (const int*)d_in[4];

    char* ws = (char*)d_ws;
    int* deg_out  = (int*)(ws + OFF_DEGOUT);
    int* deg_in   = (int*)(ws + OFF_DEGIN);
    int* row_ptr  = (int*)(ws + OFF_ROWPTR);
    int* bpart    = (int*)(ws + OFF_BPART);
    int* blockoff = (int*)(ws + OFF_BLOCKOFF);
    int* bsums    = (int*)(ws + OFF_BSUMS);
    int* flag     = (int*)(ws + OFF_FLAG);
    unsigned int* esort = (unsigned int*)(ws + OFF_ESORT);
    unsigned int* part  = (unsigned int*)(ws + OFF_PART);
    __hip_bfloat16* hs  = (__hip_bfloat16*)(ws + OFF_HS);

    detect_kernel<<<1, 256, 0, stream>>>(x, flag);

    hist_kernel<<<dim3(HB, 2, 2), 1024, 0, stream>>>(src, dst, part);
    reduce_deg_kernel<<<(2 * HALF_WORDS + 255) / 256, 256, 0, stream>>>(part, deg_out, deg_in);

    scanA_kernel<<<NB_SCAN, 256, 0, stream>>>(deg_in, row_ptr, bsums);
    scanB_kernel<<<1, 256, 0, stream>>>(bsums);
    scanC_kernel<<<NB_SCAN, 256, 0, stream>>>(row_ptr, bsums);

    gemm_scale_kernel<<<2048, 256, 0, stream>>>(x, W, deg_out, flag, hs);

    bcount_kernel<<<HB, 1024, 0, stream>>>(dst, bpart);
    boffset_kernel<<<(KBUK + 255) / 256, 256, 0, stream>>>(bpart, row_ptr, blockoff);
    semisort_kernel<<<HB, 1024, 0, stream>>>(src, dst, blockoff, esort);

    bucket_gather_kernel<<<KBUK, 1024, 0, stream>>>(hs, row_ptr, esort, deg_in, b, flag, d_out);
}

// Round 6
// 208.987 us; speedup vs baseline: 3.3755x; 3.3755x over previous
//
#include <hip/hip_runtime.h>
#include <hip/hip_bf16.h>

#define N_NODES 100000
#define N_EDGES 1200000
#define DCH 64

// Edge-chunk config shared by hist / bcount / semisort.
#define HB 96
#define CHUNK ((N_EDGES + HB - 1) / HB)        // 12500 edges per chunk-block
#define HALF_BINS 50000
#define HALF_WORDS 12500

// Bucketing: 256 nodes per bucket.
#define BNODES 256
#define KBUK ((N_NODES + BNODES - 1) / BNODES)   // 391

// Workspace layout (bytes), total ~23.5 MB (26.4 MB known-safe):
//   deg_out  : int N          [0,         400000)
//   row_ptr  : int N+1        [400000,    800004)
//   bpart    : int HB*KBUK    [800008,    950152)
//   blockoff : int HB*KBUK    [950152,   1100296)
//   flag     : int 1          [1100296,  1100300)
//   esort    : u32 E          [1100304,  5900304)
//   esrc2    : u32 E          [5900304, 10700304)
//   hs       : bf16 N*64     [10700304, 23500304)
//   part     : hist partials (9.6 MB) overlays esort+esrc2; dead after reduce
#define OFF_DEGOUT   0
#define OFF_ROWPTR   400000
#define OFF_BPART    800008
#define OFF_BLOCKOFF 950152
#define OFF_FLAG     1100296
#define OFF_ESORT    1100304
#define OFF_ESRC2    5900304
#define OFF_HS       10700304
#define OFF_PART     1100304   // = OFF_ESORT; consumed before esort/esrc2 written

__device__ __forceinline__ float load_f(const void* p, int i, int f32) {
    if (f32) return ((const float*)p)[i];
    return __bfloat162float(((const __hip_bfloat16*)p)[i]);
}

// Runtime dtype sniff (resolved fp32 on this harness; kept for safety).
__global__ void detect_kernel(const void* __restrict__ x, int* __restrict__ flag) {
    __shared__ int cnt[256];
    int tid = threadIdx.x;
    const unsigned short* u = (const unsigned short*)x;
    int c = 0;
    for (int i = tid * 16; i < tid * 16 + 16; ++i) {
        unsigned short v = u[2 * i];
        int e = (v >> 7) & 0xFF;
        if (e >= 141) c++;
    }
    cnt[tid] = c;
    __syncthreads();
    for (int s = 128; s > 0; s >>= 1) {
        if (tid < s) cnt[tid] += cnt[tid + s];
        __syncthreads();
    }
    if (tid == 0) *flag = (cnt[0] > 256) ? 1 : 0;
}

// Per-block LDS byte-counter out-degree histogram over src (no fabric atomics).
__global__ __launch_bounds__(1024)
void hist_src_kernel(const int* __restrict__ src, unsigned int* __restrict__ part) {
    __shared__ unsigned int h[HALF_WORDS];   // 50 KB
    int tid = threadIdx.x;
    int b = blockIdx.x, half = blockIdx.y;
    for (int w = tid; w < HALF_WORDS; w += 1024) h[w] = 0;
    __syncthreads();
    int lo = half * HALF_BINS, hi = lo + HALF_BINS;
    int e0 = b * CHUNK;
    int e1 = e0 + CHUNK; if (e1 > N_EDGES) e1 = N_EDGES;
    for (int e = e0 + tid; e < e1; e += 1024) {
        int n = src[e];
        if (n >= lo && n < hi) {
            int r = n - lo;
            atomicAdd(&h[r >> 2], 1u << ((r & 3) * 8));
        }
    }
    __syncthreads();
    unsigned int* slice = part + (size_t)(b * 2 + half) * HALF_WORDS;
    for (int w = tid; w < HALF_WORDS; w += 1024) slice[w] = h[w];
}

// Sum packed-byte partials -> deg_out (byte lanes can't carry: max deg ~40).
__global__ void reduce_degout_kernel(const unsigned int* __restrict__ part,
                                     int* __restrict__ deg_out) {
    int g = blockIdx.x * 256 + threadIdx.x;
    if (g >= 2 * HALF_WORDS) return;
    int half = (g >= HALF_WORDS) ? 1 : 0;
    int w = g - half * HALF_WORDS;
    unsigned int acc = 0;
    for (int b = 0; b < HB; ++b)
        acc += part[(size_t)(b * 2 + half) * HALF_WORDS + w];
    int node = half * HALF_BINS + w * 4;
#pragma unroll
    for (int j = 0; j < 4; ++j)
        deg_out[node + j] = (int)((acc >> (j * 8)) & 0xFF);
}

// hs[i][c] = bf16( (x[i]@W)[c] * rsqrt(max(deg_out[i],1)) )
// Wave-per-node; W column in regs; x broadcast via readlane; 4 FMA chains.
__global__ void gemm_scale_kernel(const void* __restrict__ x,
                                  const void* __restrict__ W,
                                  const int* __restrict__ deg_out,
                                  const int* __restrict__ flag,
                                  __hip_bfloat16* __restrict__ hs) {
    int f32 = *flag;
    int lane = threadIdx.x & 63;
    int wave = (blockIdx.x * blockDim.x + threadIdx.x) >> 6;
    int nwaves = (gridDim.x * blockDim.x) >> 6;

    float wcol[DCH];
#pragma unroll
    for (int k = 0; k < DCH; ++k)
        wcol[k] = load_f(W, k * DCH + lane, f32);

    for (int node = wave; node < N_NODES; node += nwaves) {
        float xv = load_f(x, node * DCH + lane, f32);
        float s0 = 0.0f, s1 = 0.0f, s2 = 0.0f, s3 = 0.0f;
#pragma unroll
        for (int k = 0; k < DCH; k += 4) {
            float x0 = __int_as_float(__builtin_amdgcn_readlane(__float_as_int(xv), k + 0));
            float x1 = __int_as_float(__builtin_amdgcn_readlane(__float_as_int(xv), k + 1));
            float x2 = __int_as_float(__builtin_amdgcn_readlane(__float_as_int(xv), k + 2));
            float x3 = __int_as_float(__builtin_amdgcn_readlane(__float_as_int(xv), k + 3));
            s0 = fmaf(x0, wcol[k + 0], s0);
            s1 = fmaf(x1, wcol[k + 1], s1);
            s2 = fmaf(x2, wcol[k + 2], s2);
            s3 = fmaf(x3, wcol[k + 3], s3);
        }
        float sum = (s0 + s1) + (s2 + s3);
        float nrm = rsqrtf(fmaxf((float)deg_out[node], 1.0f));
        hs[node * DCH + lane] = __float2bfloat16(sum * nrm);
    }
}

// B1: per-chunk dst-bucket counts (LDS int atomics only).
__global__ __launch_bounds__(1024)
void bcount_kernel(const int* __restrict__ dst, int* __restrict__ bpart) {
    __shared__ int cnt[KBUK];
    int tid = threadIdx.x, blk = blockIdx.x;
    for (int i = tid; i < KBUK; i += 1024) cnt[i] = 0;
    __syncthreads();
    int e0 = blk * CHUNK;
    int e1 = e0 + CHUNK; if (e1 > N_EDGES) e1 = N_EDGES;
    for (int e = e0 + tid; e < e1; e += 1024)
        atomicAdd(&cnt[dst[e] >> 8], 1);
    __syncthreads();
    for (int i = tid; i < KBUK; i += 1024) bpart[blk * KBUK + i] = cnt[i];
}

// B2: single block. Bucket totals -> exclusive bucket bases -> per-(chunk,
// bucket) write offsets. blockoff[0*KBUK+k] is bucket k's global base.
__global__ __launch_bounds__(512)
void bscan_kernel(const int* __restrict__ bpart, int* __restrict__ blockoff) {
    __shared__ int s[512];
    int k = threadIdx.x;
    int tot = 0;
    if (k < KBUK)
        for (int b = 0; b < HB; ++b) tot += bpart[b * KBUK + k];
    s[k] = tot;
    __syncthreads();
    for (int off = 1; off < 512; off <<= 1) {
        int add = (k >= off) ? s[k - off] : 0;
        __syncthreads();
        s[k] += add;
        __syncthreads();
    }
    if (k < KBUK) {
        int run = s[k] - tot;   // exclusive base
        for (int b = 0; b < HB; ++b) {
            blockoff[b * KBUK + k] = run;
            run += bpart[b * KBUK + k];
        }
    }
}

// B3: semi-sort edges into dst-bucket order with LDS int cursors.
// Packed u32: bits 0..23 = src (<100000), bits 24..31 = dst & 255.
__global__ __launch_bounds__(1024)
void semisort_kernel(const int* __restrict__ src,
                     const int* __restrict__ dst,
                     const int* __restrict__ blockoff,
                     unsigned int* __restrict__ esort) {
    __shared__ int cur[KBUK];
    int tid = threadIdx.x, blk = blockIdx.x;
    for (int i = tid; i < KBUK; i += 1024) cur[i] = blockoff[blk * KBUK + i];
    __syncthreads();
    int e0 = blk * CHUNK;
    int e1 = e0 + CHUNK; if (e1 > N_EDGES) e1 = N_EDGES;
    for (int e = e0 + tid; e < e1; e += 1024) {
        int d = dst[e];
        int pos = atomicAdd(&cur[d >> 8], 1);
        esort[pos] = (unsigned int)src[e] | ((unsigned int)(d & 255) << 24);
    }
}

// B4: per-bucket exact sort by node -> CSR (esrc2 + row_ptr).
// 256-entry LDS histogram + LDS scan; writes land in the bucket's ~12 KB span.
__global__ __launch_bounds__(256)
void nodesort_kernel(const unsigned int* __restrict__ esort,
                     const int* __restrict__ blockoff,
                     unsigned int* __restrict__ esrc2,
                     int* __restrict__ row_ptr) {
    __shared__ int cnt[BNODES];
    __shared__ int loc[BNODES];
    __shared__ int sc[BNODES];
    int k = blockIdx.x, t = threadIdx.x;
    int bbase = blockoff[k];                                   // blockoff[0][k]
    int bend  = (k + 1 < KBUK) ? blockoff[k + 1] : N_EDGES;    // next bucket base
    cnt[t] = 0;
    __syncthreads();
    for (int e = bbase + t; e < bend; e += 256)
        atomicAdd(&cnt[esort[e] >> 24], 1);
    __syncthreads();
    int v = cnt[t];
    sc[t] = v;
    __syncthreads();
    for (int off = 1; off < 256; off <<= 1) {
        int add = (t >= off) ? sc[t - off] : 0;
        __syncthreads();
        sc[t] += add;
        __syncthreads();
    }
    loc[t] = sc[t] - v;   // exclusive within bucket
    __syncthreads();
    int nlo = k * BNODES;
    if (nlo + t < N_NODES) row_ptr[nlo + t] = bbase + loc[t];
    if (k == KBUK - 1 && t == 0) row_ptr[N_NODES] = N_EDGES;
    cnt[t] = 0;   // reuse as cursor
    __syncthreads();
    for (int e = bbase + t; e < bend; e += 256) {
        unsigned int w = esort[e];
        int r = w >> 24;
        int pos = bbase + loc[r] + atomicAdd(&cnt[r], 1);
        esrc2[pos] = w & 0xFFFFFFu;
    }
}

// G: wave per node, register accumulation, 4-edge unroll with 4 independent
// accumulator chains for MLP. Fused norm+bias+relu+store.
__global__ __launch_bounds__(256)
void gather_kernel(const __hip_bfloat16* __restrict__ hs,
                   const int* __restrict__ row_ptr,
                   const unsigned int* __restrict__ esrc2,
                   const void* __restrict__ b,
                   const int* __restrict__ flag,
                   void* __restrict__ out) {
    int f32 = *flag;
    int lane = threadIdx.x & 63;
    int node = (blockIdx.x * blockDim.x + threadIdx.x) >> 6;
    if (node >= N_NODES) return;
    int beg = row_ptr[node];
    int end = row_ptr[node + 1];
    const unsigned short* hsu = (const unsigned short*)hs;
    float a0 = 0.0f, a1 = 0.0f, a2 = 0.0f, a3 = 0.0f;
    for (int j0 = beg; j0 < end; j0 += 64) {
        int nj = end - j0; if (nj > 64) nj = 64;
        int sid = (lane < nj) ? (int)esrc2[j0 + lane] : 0;
        int j = 0;
        for (; j + 4 <= nj; j += 4) {
            int s0 = __shfl(sid, j), s1 = __shfl(sid, j + 1);
            int s2 = __shfl(sid, j + 2), s3 = __shfl(sid, j + 3);
            unsigned short r0 = hsu[s0 * DCH + lane];
            unsigned short r1 = hsu[s1 * DCH + lane];
            unsigned short r2 = hsu[s2 * DCH + lane];
            unsigned short r3 = hsu[s3 * DCH + lane];
            a0 += __uint_as_float((unsigned int)r0 << 16);
            a1 += __uint_as_float((unsigned int)r1 << 16);
            a2 += __uint_as_float((unsigned int)r2 << 16);
            a3 += __uint_as_float((unsigned int)r3 << 16);
        }
        for (; j < nj; ++j) {
            int s = __shfl(sid, j);
            a0 += __uint_as_float((unsigned int)hsu[s * DCH + lane] << 16);
        }
    }
    float acc = (a0 + a1) + (a2 + a3);
    float nrm = rsqrtf(fmaxf((float)(end - beg), 1.0f));
    float v = fmaxf(acc * nrm + load_f(b, lane, f32), 0.0f);
    int oi = node * DCH + lane;
    if (f32) ((float*)out)[oi] = v;
    else     ((__hip_bfloat16*)out)[oi] = __float2bfloat16(v);
}

extern "C" void kernel_launch(void* const* d_in, const int* in_sizes, int n_in,
                              void* d_out, int out_size, void* d_ws, size_t ws_size,
                              hipStream_t stream) {
    const void* x   = d_in[0];
    const void* W   = d_in[1];
    const void* b   = d_in[2];
    const int*  src = (const int*)d_in[3];
    const int*  dst = (const int*)d_in[4];

    char* ws = (char*)d_ws;
    int* deg_out  = (int*)(ws + OFF_DEGOUT);
    int* row_ptr  = (int*)(ws + OFF_ROWPTR);
    int* bpart    = (int*)(ws + OFF_BPART);
    int* blockoff = (int*)(ws + OFF_BLOCKOFF);
    int* flag     = (int*)(ws + OFF_FLAG);
    unsigned int* esort = (unsigned int*)(ws + OFF_ESORT);
    unsigned int* esrc2 = (unsigned int*)(ws + OFF_ESRC2);
    unsigned int* part  = (unsigned int*)(ws + OFF_PART);
    __hip_bfloat16* hs  = (__hip_bfloat16*)(ws + OFF_HS);

    detect_kernel<<<1, 256, 0, stream>>>(x, flag);

    // Out-degree via LDS byte-counter histogram (src only).
    hist_src_kernel<<<dim3(HB, 2), 1024, 0, stream>>>(src, part);
    reduce_degout_kernel<<<(2 * HALF_WORDS + 255) / 256, 256, 0, stream>>>(part, deg_out);

    gemm_scale_kernel<<<2048, 256, 0, stream>>>(x, W, deg_out, flag, hs);

    // Exact CSR without fabric atomics: bucket semisort + per-bucket node sort.
    bcount_kernel<<<HB, 1024, 0, stream>>>(dst, bpart);
    bscan_kernel<<<1, 512, 0, stream>>>(bpart, blockoff);
    semisort_kernel<<<HB, 1024, 0, stream>>>(src, dst, blockoff, esort);
    nodesort_kernel<<<KBUK, 256, 0, stream>>>(esort, blockoff, esrc2, row_ptr);

    gather_kernel<<<(N_NODES * 64 + 255) / 256, 256, 0, stream>>>(
        hs, row_ptr, esrc2, b, flag, d_out);
}

// Round 7
// 204.263 us; speedup vs baseline: 3.4536x; 1.0231x over previous
//
#include <hip/hip_runtime.h>
#include <hip/hip_bf16.h>

#define N_NODES 100000
#define N_EDGES 1200000
#define DCH 64

// Edge-chunk config shared by edges_kernel / semisort.
#define HB 96
#define CHUNK ((N_EDGES + HB - 1) / HB)        // 12500 edges per chunk-block
#define HALF_BINS 50000
#define HALF_WORDS 12500                        // u32 words per half (4 bins/word)

// Bucketing: 256 nodes per bucket.
#define BNODES 256
#define KBUK ((N_NODES + BNODES - 1) / BNODES)   // 391

// Workspace layout (bytes), all arrays 256B-aligned, total 23.2 MB (<26.4 safe):
//   deg_packed : u32 25000   [0,        100000)   byte-packed out-degrees
//   row_ptr    : int N+1     [102400,   502404)
//   bpart      : int HB*KBUK [512000,   662144)
//   blockoff   : int HB*KBUK [665600,   815744)
//   flag       : int 1       [819200,   819204)
//   esort      : u32 E       [819456,  5619456)
//   esrc2      : u32 E       [5619712, 10419712)
//   hs         : bf16 N*64  [10419712, 23219712)  rows 128B-aligned (1 line/row)
#define OFF_DEG      0
#define OFF_ROWPTR   102400
#define OFF_BPART    512000
#define OFF_BLOCKOFF 665600
#define OFF_FLAG     819200
#define OFF_ESORT    819456
#define OFF_ESRC2    5619712
#define OFF_HS       10419712

__device__ __forceinline__ float load_f(const void* p, int i, int f32) {
    if (f32) return ((const float*)p)[i];
    return __bfloat162float(((const __hip_bfloat16*)p)[i]);
}

// Runtime dtype sniff (resolved fp32 on this harness; kept for safety).
__global__ void detect_kernel(const void* __restrict__ x, int* __restrict__ flag) {
    __shared__ int cnt[256];
    int tid = threadIdx.x;
    const unsigned short* u = (const unsigned short*)x;
    int c = 0;
    for (int i = tid * 16; i < tid * 16 + 16; ++i) {
        unsigned short v = u[2 * i];
        int e = (v >> 7) & 0xFF;
        if (e >= 141) c++;
    }
    cnt[tid] = c;
    __syncthreads();
    for (int s = 128; s > 0; s >>= 1) {
        if (tid < s) cnt[tid] += cnt[tid + s];
        __syncthreads();
    }
    if (tid == 0) *flag = (cnt[0] > 256) ? 1 : 0;
}

// Fused degree-histogram + dst-bucket-count, one pass over the edge chunk.
// grid (HB, 2): y = src node-half. Byte counters in LDS (max deg ~40 << 255);
// flushed with COALESCED packed-u32 global atomics (contiguous addresses ->
// ~16 words/line, unlike the R2/R3 random-line atomic disaster).
__global__ __launch_bounds__(1024)
void edges_kernel(const int* __restrict__ src,
                  const int* __restrict__ dst,
                  unsigned int* __restrict__ deg_packed,
                  int* __restrict__ bpart) {
    __shared__ unsigned int h[HALF_WORDS];   // 50 KB
    __shared__ int cnt[KBUK];
    int tid = threadIdx.x, b = blockIdx.x, half = blockIdx.y;
    for (int w = tid; w < HALF_WORDS; w += 1024) h[w] = 0;
    if (half == 0)
        for (int i = tid; i < KBUK; i += 1024) cnt[i] = 0;
    __syncthreads();
    int lo = half * HALF_BINS;
    int e0 = b * CHUNK;
    int e1 = e0 + CHUNK; if (e1 > N_EDGES) e1 = N_EDGES;
    for (int e = e0 + tid; e < e1; e += 1024) {
        int n = src[e] - lo;
        if ((unsigned)n < (unsigned)HALF_BINS)
            atomicAdd(&h[n >> 2], 1u << ((n & 3) * 8));
        if (half == 0)
            atomicAdd(&cnt[dst[e] >> 8], 1);
    }
    __syncthreads();
    unsigned int* dp = deg_packed + half * HALF_WORDS;
    for (int w = tid; w < HALF_WORDS; w += 1024) {
        unsigned int v = h[w];
        if (v) atomicAdd(&dp[w], v);   // coalesced line-RMWs
    }
    if (half == 0)
        for (int i = tid; i < KBUK; i += 1024) bpart[b * KBUK + i] = cnt[i];
}

// hs[i][c] = bf16( (x[i]@W)[c] * rsqrt(max(deg_out[i],1)) )
// Wave-per-node; W column in regs; x broadcast via readlane; 4 FMA chains.
__global__ void gemm_scale_kernel(const void* __restrict__ x,
                                  const void* __restrict__ W,
                                  const unsigned int* __restrict__ deg_packed,
                                  const int* __restrict__ flag,
                                  __hip_bfloat16* __restrict__ hs) {
    int f32 = *flag;
    int lane = threadIdx.x & 63;
    int wave = (blockIdx.x * blockDim.x + threadIdx.x) >> 6;
    int nwaves = (gridDim.x * blockDim.x) >> 6;

    float wcol[DCH];
#pragma unroll
    for (int k = 0; k < DCH; ++k)
        wcol[k] = load_f(W, k * DCH + lane, f32);

    for (int node = wave; node < N_NODES; node += nwaves) {
        float xv = load_f(x, node * DCH + lane, f32);
        float s0 = 0.0f, s1 = 0.0f, s2 = 0.0f, s3 = 0.0f;
#pragma unroll
        for (int k = 0; k < DCH; k += 4) {
            float x0 = __int_as_float(__builtin_amdgcn_readlane(__float_as_int(xv), k + 0));
            float x1 = __int_as_float(__builtin_amdgcn_readlane(__float_as_int(xv), k + 1));
            float x2 = __int_as_float(__builtin_amdgcn_readlane(__float_as_int(xv), k + 2));
            float x3 = __int_as_float(__builtin_amdgcn_readlane(__float_as_int(xv), k + 3));
            s0 = fmaf(x0, wcol[k + 0], s0);
            s1 = fmaf(x1, wcol[k + 1], s1);
            s2 = fmaf(x2, wcol[k + 2], s2);
            s3 = fmaf(x3, wcol[k + 3], s3);
        }
        float sum = (s0 + s1) + (s2 + s3);
        unsigned int dw = deg_packed[node >> 2];
        float deg = (float)((dw >> ((node & 3) * 8)) & 0xFFu);
        float nrm = rsqrtf(fmaxf(deg, 1.0f));
        hs[node * DCH + lane] = __float2bfloat16(sum * nrm);
    }
}

// Single block: bucket totals -> exclusive bases -> per-(chunk,bucket) offsets.
__global__ __launch_bounds__(512)
void bscan_kernel(const int* __restrict__ bpart, int* __restrict__ blockoff) {
    __shared__ int s[512];
    int k = threadIdx.x;
    int tot = 0;
    if (k < KBUK)
        for (int b = 0; b < HB; ++b) tot += bpart[b * KBUK + k];
    s[k] = tot;
    __syncthreads();
    for (int off = 1; off < 512; off <<= 1) {
        int add = (k >= off) ? s[k - off] : 0;
        __syncthreads();
        s[k] += add;
        __syncthreads();
    }
    if (k < KBUK) {
        int run = s[k] - tot;   // exclusive base
        for (int b = 0; b < HB; ++b) {
            blockoff[b * KBUK + k] = run;
            run += bpart[b * KBUK + k];
        }
    }
}

// Semi-sort edges into dst-bucket order with LDS int cursors.
// Packed u32: bits 0..23 = src (<100000), bits 24..31 = dst & 255.
__global__ __launch_bounds__(1024)
void semisort_kernel(const int* __restrict__ src,
                     const int* __restrict__ dst,
                     const int* __restrict__ blockoff,
                     unsigned int* __restrict__ esort) {
    __shared__ int cur[KBUK];
    int tid = threadIdx.x, blk = blockIdx.x;
    for (int i = tid; i < KBUK; i += 1024) cur[i] = blockoff[blk * KBUK + i];
    __syncthreads();
    int e0 = blk * CHUNK;
    int e1 = e0 + CHUNK; if (e1 > N_EDGES) e1 = N_EDGES;
    for (int e = e0 + tid; e < e1; e += 1024) {
        int d = dst[e];
        int pos = atomicAdd(&cur[d >> 8], 1);
        esort[pos] = (unsigned int)src[e] | ((unsigned int)(d & 255) << 24);
    }
}

// Per-bucket exact sort by node -> CSR (esrc2 + row_ptr).
__global__ __launch_bounds__(256)
void nodesort_kernel(const unsigned int* __restrict__ esort,
                     const int* __restrict__ blockoff,
                     unsigned int* __restrict__ esrc2,
                     int* __restrict__ row_ptr) {
    __shared__ int cnt[BNODES];
    __shared__ int loc[BNODES];
    __shared__ int sc[BNODES];
    int k = blockIdx.x, t = threadIdx.x;
    int bbase = blockoff[k];                                   // blockoff[0][k]
    int bend  = (k + 1 < KBUK) ? blockoff[k + 1] : N_EDGES;
    cnt[t] = 0;
    __syncthreads();
    for (int e = bbase + t; e < bend; e += 256)
        atomicAdd(&cnt[esort[e] >> 24], 1);
    __syncthreads();
    int v = cnt[t];
    sc[t] = v;
    __syncthreads();
    for (int off = 1; off < 256; off <<= 1) {
        int add = (t >= off) ? sc[t - off] : 0;
        __syncthreads();
        sc[t] += add;
        __syncthreads();
    }
    loc[t] = sc[t] - v;
    __syncthreads();
    int nlo = k * BNODES;
    if (nlo + t < N_NODES) row_ptr[nlo + t] = bbase + loc[t];
    if (k == KBUK - 1 && t == 0) row_ptr[N_NODES] = N_EDGES;
    cnt[t] = 0;   // reuse as cursor
    __syncthreads();
    for (int e = bbase + t; e < bend; e += 256) {
        unsigned int w = esort[e];
        int r = w >> 24;
        int pos = bbase + loc[r] + atomicAdd(&cnt[r], 1);
        esrc2[pos] = w & 0xFFFFFFu;
    }
}

// Wave per node, register accumulation, 8 independent chains for MLP.
__global__ __launch_bounds__(256)
void gather_kernel(const __hip_bfloat16* __restrict__ hs,
                   const int* __restrict__ row_ptr,
                   const unsigned int* __restrict__ esrc2,
                   const void* __restrict__ b,
                   const int* __restrict__ flag,
                   void* __restrict__ out) {
    int f32 = *flag;
    int lane = threadIdx.x & 63;
    int node = (blockIdx.x * blockDim.x + threadIdx.x) >> 6;
    if (node >= N_NODES) return;
    int beg = row_ptr[node];
    int end = row_ptr[node + 1];
    const unsigned short* hsu = (const unsigned short*)hs;
    float a0 = 0.f, a1 = 0.f, a2 = 0.f, a3 = 0.f;
    float a4 = 0.f, a5 = 0.f, a6 = 0.f, a7 = 0.f;
    for (int j0 = beg; j0 < end; j0 += 64) {
        int nj = end - j0; if (nj > 64) nj = 64;
        int sid = (lane < nj) ? (int)esrc2[j0 + lane] : 0;
        int j = 0;
        for (; j + 8 <= nj; j += 8) {
            int s0 = __shfl(sid, j + 0), s1 = __shfl(sid, j + 1);
            int s2 = __shfl(sid, j + 2), s3 = __shfl(sid, j + 3);
            int s4 = __shfl(sid, j + 4), s5 = __shfl(sid, j + 5);
            int s6 = __shfl(sid, j + 6), s7 = __shfl(sid, j + 7);
            unsigned short r0 = hsu[s0 * DCH + lane];
            unsigned short r1 = hsu[s1 * DCH + lane];
            unsigned short r2 = hsu[s2 * DCH + lane];
            unsigned short r3 = hsu[s3 * DCH + lane];
            unsigned short r4 = hsu[s4 * DCH + lane];
            unsigned short r5 = hsu[s5 * DCH + lane];
            unsigned short r6 = hsu[s6 * DCH + lane];
            unsigned short r7 = hsu[s7 * DCH + lane];
            a0 += __uint_as_float((unsigned int)r0 << 16);
            a1 += __uint_as_float((unsigned int)r1 << 16);
            a2 += __uint_as_float((unsigned int)r2 << 16);
            a3 += __uint_as_float((unsigned int)r3 << 16);
            a4 += __uint_as_float((unsigned int)r4 << 16);
            a5 += __uint_as_float((unsigned int)r5 << 16);
            a6 += __uint_as_float((unsigned int)r6 << 16);
            a7 += __uint_as_float((unsigned int)r7 << 16);
        }
        for (; j + 4 <= nj; j += 4) {
            int s0 = __shfl(sid, j + 0), s1 = __shfl(sid, j + 1);
            int s2 = __shfl(sid, j + 2), s3 = __shfl(sid, j + 3);
            unsigned short r0 = hsu[s0 * DCH + lane];
            unsigned short r1 = hsu[s1 * DCH + lane];
            unsigned short r2 = hsu[s2 * DCH + lane];
            unsigned short r3 = hsu[s3 * DCH + lane];
            a0 += __uint_as_float((unsigned int)r0 << 16);
            a1 += __uint_as_float((unsigned int)r1 << 16);
            a2 += __uint_as_float((unsigned int)r2 << 16);
            a3 += __uint_as_float((unsigned int)r3 << 16);
        }
        for (; j < nj; ++j) {
            int s = __shfl(sid, j);
            a0 += __uint_as_float((unsigned int)hsu[s * DCH + lane] << 16);
        }
    }
    float acc = ((a0 + a1) + (a2 + a3)) + ((a4 + a5) + (a6 + a7));
    float nrm = rsqrtf(fmaxf((float)(end - beg), 1.0f));
    float v = fmaxf(acc * nrm + load_f(b, lane, f32), 0.0f);
    int oi = node * DCH + lane;
    if (f32) ((float*)out)[oi] = v;
    else     ((__hip_bfloat16*)out)[oi] = __float2bfloat16(v);
}

extern "C" void kernel_launch(void* const* d_in, const int* in_sizes, int n_in,
                              void* d_out, int out_size, void* d_ws, size_t ws_size,
                              hipStream_t stream) {
    const void* x   = d_in[0];
    const void* W   = d_in[1];
    const void* b   = d_in[2];
    const int*  src = (const int*)d_in[3];
    const int*  dst = (const int*)d_in[4];

    char* ws = (char*)d_ws;
    unsigned int* deg_packed = (unsigned int*)(ws + OFF_DEG);
    int* row_ptr  = (int*)(ws + OFF_ROWPTR);
    int* bpart    = (int*)(ws + OFF_BPART);
    int* blockoff = (int*)(ws + OFF_BLOCKOFF);
    int* flag     = (int*)(ws + OFF_FLAG);
    unsigned int* esort = (unsigned int*)(ws + OFF_ESORT);
    unsigned int* esrc2 = (unsigned int*)(ws + OFF_ESRC2);
    __hip_bfloat16* hs  = (__hip_bfloat16*)(ws + OFF_HS);

    hipMemsetAsync(deg_packed, 0, 2 * HALF_WORDS * 4, stream);   // 100 KB

    detect_kernel<<<1, 256, 0, stream>>>(x, flag);

    // Fused out-degree histogram + dst-bucket counts (one edge pass).
    edges_kernel<<<dim3(HB, 2), 1024, 0, stream>>>(src, dst, deg_packed, bpart);

    gemm_scale_kernel<<<2048, 256, 0, stream>>>(x, W, deg_packed, flag, hs);

    bscan_kernel<<<1, 512, 0, stream>>>(bpart, blockoff);
    semisort_kernel<<<HB, 1024, 0, stream>>>(src, dst, blockoff, esort);
    nodesort_kernel<<<KBUK, 256, 0, stream>>>(esort, blockoff, esrc2, row_ptr);

    gather_kernel<<<(N_NODES * 64 + 255) / 256, 256, 0, stream>>>(
        hs, row_ptr, esrc2, b, flag, d_out);
}